// Round 14
// baseline (186.552 us; speedup 1.0000x reference)
//
#include <hip/hip_runtime.h>
#include <hip/hip_bf16.h>
#include <hip/hip_fp16.h>

#define NN 384
#define CC 128
#define PP (NN*NN)      // 147456 positions
#define PB 64           // positions per block
#define NB (PP/PB)      // 2304 blocks
#define TPB 256         // 4 waves; each wave owns one 16-row stripe (16x16x32 MFMA)

typedef __attribute__((ext_vector_type(8))) short bf16x8;
typedef __attribute__((ext_vector_type(4))) float f32x4;
typedef __attribute__((ext_vector_type(8))) unsigned short u16x8;

// 8 weight planes (32KB each) in PHASE order:
// 0 AGH, 1 APH, 2 APL, 3 BGH, 4 BPH, 5 BPL, 6 G, 7 Z
// Plane layout (R7/R12-proven): chunk (k0*8+n)*64+l holds
// W[n*16+(l&15)][k0*32+(l>>4)*8 .. +7], k0 in [0,4).
// Quarter q = bytes [q*8192, q*8192+8192).

__device__ __forceinline__ unsigned short f2bf(float f){
  __hip_bfloat16 h = __float2bfloat16(f);
  return __builtin_bit_cast(unsigned short, h);
}
__device__ __forceinline__ float bf2f(unsigned h){ return __uint_as_float(h<<16); }
__device__ __forceinline__ unsigned pack2(float a, float b){
  return (unsigned)f2bf(a) | ((unsigned)f2bf(b)<<16);
}
__device__ __forceinline__ float sigmoidf_(float x){
  return __fdividef(1.0f, 1.0f + __expf(-x));
}
__device__ __forceinline__ unsigned short f2h(float f){
  __half h = __float2half(f);
  return __builtin_bit_cast(unsigned short, h);
}
__device__ __forceinline__ float h2f(unsigned short u){
  __half h = __builtin_bit_cast(__half, u);
  return __half2float(h);
}

// ---------------------------------------------------------------------------
__global__ __launch_bounds__(256) void k0_wprep(
    const float* __restrict__ wap, const float* __restrict__ wag,
    const float* __restrict__ wbp, const float* __restrict__ wbg,
    const float* __restrict__ wg,  const float* __restrict__ wz,
    unsigned short* __restrict__ wfrag){
  int tid = blockIdx.x*256 + threadIdx.x;      // 0..16383
  int plane = tid >> 11, chunk = tid & 2047;
  const float* W = (plane==0) ? wag
                 : (plane==1||plane==2) ? wap
                 : (plane==3) ? wbg
                 : (plane==4||plane==5) ? wbp
                 : (plane==6) ? wg : wz;
  bool lo = (plane==2)||(plane==5);
  int k0 = chunk >> 9, n = (chunk >> 6) & 7, l = chunk & 63;
  int o  = n*16 + (l & 15);
  int kb = k0*32 + ((l>>4)<<3);
  const float* s = W + o*128 + kb;
  u16x8 v;
  #pragma unroll
  for (int e=0;e<8;e++){
    float w = s[e];
    unsigned short hh = f2bf(w);
    v[e] = lo ? f2bf(w - bf2f(hh)) : hh;
  }
  *(u16x8*)(wfrag + (size_t)tid*8) = v;
}

// ---------------------------------------------------------------------------
// Stage one 8KB plane-quarter into a slot (global_load_lds, zero staging regs).
// ---------------------------------------------------------------------------
__device__ __forceinline__ void stage_q(const unsigned char* __restrict__ src_base,
                                        unsigned char* slot, int t){
  int wv = t>>6, l = t&63;
  const unsigned char* src = src_base + wv*2048 + l*16;
  unsigned char* dst = slot + wv*2048;
  #pragma unroll
  for (int i=0;i<2;i++)
    __builtin_amdgcn_global_load_lds(
        (const __attribute__((address_space(1))) unsigned int*)(src + i*1024),
        (__attribute__((address_space(3))) unsigned int*)(dst + i*1024),
        16, 0, 0);
}

// ---------------------------------------------------------------------------
// Quarter passes (k0=q fixed): 8 n-frags. Slot offset n*1024 + l*16.
// A-frag: row=row0+(l&15), k=q*32+(l>>4)*8+e. D: row=row0+(l>>4)*4+r, col=n*16+(l&15).
// ---------------------------------------------------------------------------
__device__ __forceinline__ void q_H(const bf16x8* a, int q,
    const unsigned char* slot, int l, f32x4* acc){
  #pragma unroll
  for (int n=0;n<8;n++){
    bf16x8 f = *(const bf16x8*)(slot + n*1024 + l*16);
    acc[n] = __builtin_amdgcn_mfma_f32_16x16x32_bf16(a[q], f, acc[n], 0,0,0);
  }
}
__device__ __forceinline__ void q_HL(const bf16x8* aH, const bf16x8* aL, int q,
    const unsigned char* slot, int l, f32x4* acc){
  #pragma unroll
  for (int n=0;n<8;n++){
    bf16x8 f = *(const bf16x8*)(slot + n*1024 + l*16);
    acc[n] = __builtin_amdgcn_mfma_f32_16x16x32_bf16(aH[q], f, acc[n], 0,0,0);
    acc[n] = __builtin_amdgcn_mfma_f32_16x16x32_bf16(aL[q], f, acc[n], 0,0,0);
  }
}
__device__ __forceinline__ void bias_init(const float* __restrict__ b, int cb,
                                          f32x4* acc){
  #pragma unroll
  for (int n=0;n<8;n++){
    float v = b[n*16 + cb];
    f32x4 iv = {v,v,v,v};
    acc[n]=iv;
  }
}
// A-frag extraction from [row][col] XOR-swizzled bf16 tile (R7/R12-proven).
__device__ __forceinline__ void extract4(const unsigned char* base, int row0,
                                         int l, bf16x8 a[4]){
  int row = row0 + (l&15);
  int swz = (row&7)<<4;
  #pragma unroll
  for (int k0=0;k0<4;k0++){
    unsigned off = (unsigned)(row*256 + ((((l>>4)<<4) + (k0<<6)) ^ swz));
    a[k0] = *(const bf16x8*)(base + off);
  }
}

// ---------------------------------------------------------------------------
// Fused kernel: 32 quarter-phases, 2-slot rotation, stage-1-ahead.
// LDS 32KB: buf[0,16K) zn(H then L)->xa->xn, ALL wave-local ; slots [16K,32K).
// SINGLE accumulator (gates packed to gpk immediately -> accg eliminated):
// live set ~ acc32 + aH16 + aLo16 + gpk16 + temps <= 128 -> 4 waves/SIMD.
// ---------------------------------------------------------------------------
__global__ __launch_bounds__(TPB,4) void k_fused(
    const float* __restrict__ z, const float* __restrict__ mask,
    const float* __restrict__ bap, const float* __restrict__ bag,
    const float* __restrict__ bbp, const float* __restrict__ bbg,
    const float* __restrict__ bgg, const float* __restrict__ bz,
    const float* __restrict__ lniw, const float* __restrict__ lnib,
    const float* __restrict__ lnow, const float* __restrict__ lnob,
    const unsigned short* __restrict__ wfrag,
    float* __restrict__ out){
  __shared__ unsigned char lds[32768];
  unsigned char* buf = lds;             // 16KB: zn -> xa -> xn (wave-local 4K regions)
  const unsigned char* wfrag8 = (const unsigned char*)wfrag;
  const int t = threadIdx.x;
  const int pos0 = blockIdx.x * PB;
  const int wv = t>>6, l = t&63;
  const int h2 = (t>>5)&1;              // 32-lane group within wave
  const int c4 = (t&31)<<2;
  const int row0 = wv*16;

  // prologue: stage quarter 0 (AGH q0) -> slot 0
  stage_q(wfrag8, lds + 16384, t);

  // ---- P1: LN(z) WAVE-LOCAL (2 rows/iter), znH -> buf, znL packed in regs ----
  unsigned plr[16];
  {
    float4 lw = *(const float4*)(lniw + c4);
    float4 lb = *(const float4*)(lnib + c4);
    #pragma unroll
    for (int it=0; it<8; ++it){
      int row = row0 + it*2 + h2;
      float4 v = *(const float4*)(z + (size_t)(pos0+row)*CC + c4);
      float s = v.x+v.y+v.z+v.w;
      #pragma unroll
      for (int mm=1; mm<32; mm<<=1) s += __shfl_xor(s,mm);
      float mu = s*(1.0f/128.0f);
      float d0=v.x-mu, d1=v.y-mu, d2=v.z-mu, d3=v.w-mu;
      float ss = d0*d0+d1*d1+d2*d2+d3*d3;
      #pragma unroll
      for (int mm=1; mm<32; mm<<=1) ss += __shfl_xor(ss,mm);
      float rstd = rsqrtf(ss*(1.0f/128.0f) + 1e-5f);
      float n0=d0*rstd*lw.x+lb.x, n1=d1*rstd*lw.y+lb.y;
      float n2=d2*rstd*lw.z+lb.z, n3=d3*rstd*lw.w+lb.w;
      unsigned short hh0=f2bf(n0), hh1=f2bf(n1), hh2=f2bf(n2), hh3=f2bf(n3);
      unsigned off = (unsigned)(row*256 + ((c4<<1) ^ ((row&7)<<4)));
      *(uint2*)(buf + off) = make_uint2((unsigned)hh0|((unsigned)hh1<<16),
                                        (unsigned)hh2|((unsigned)hh3<<16));
      plr[it*2]   = pack2(n0-bf2f(hh0), n1-bf2f(hh1));
      plr[it*2+1] = pack2(n2-bf2f(hh2), n3-bf2f(hh3));
    }
  }
  // aH from znH (same-wave ds ordering; R8-proven pattern)
  bf16x8 aH[4], aLo[4];
  extract4(buf, row0, l, aH);
  // overwrite with znL residuals (wave-local), then aLo
  #pragma unroll
  for (int it=0; it<8; ++it){
    int row = row0 + it*2 + h2;
    unsigned off = (unsigned)(row*256 + ((c4<<1) ^ ((row&7)<<4)));
    *(uint2*)(buf + off) = make_uint2(plr[it*2], plr[it*2+1]);
  }
  extract4(buf, row0, l, aLo);

  const int cb = l&15;            // D col-within-16 / A row-within-16
  const int g4 = (l>>4)<<2;       // D row-quad base

  float mk[4];
  #pragma unroll
  for (int r=0;r<4;r++) mk[r] = mask[pos0 + row0 + g4 + r];

  f32x4 acc[8];
  unsigned gpk[16];     // packed f16 gate (32 values)

#define SL(p) (lds + 16384 + (((p)&1)<<13))
#define PH(p) do{ __syncthreads(); \
    if ((p)+1 < 32) stage_q(wfrag8 + ((size_t)((p)+1))*8192, SL((p)+1), t); }while(0)
#define PACK_GATE() do{ \
    _Pragma("unroll") \
    for (int n=0;n<8;n++) \
      _Pragma("unroll") \
      for (int rp=0;rp<2;rp++) \
        gpk[n*2+rp] = (unsigned)f2h(sigmoidf_(acc[n][2*rp])) \
                    | ((unsigned)f2h(sigmoidf_(acc[n][2*rp+1]))<<16); \
  }while(0)

  // ---- a-gate (hi-only) in acc, pack f16, then a-proj reuses acc ----
  PH(0);  bias_init(bag,cb,acc); q_H(aH,0,SL(0), l,acc);
  PH(1);  q_H(aH,1,SL(1), l,acc);
  PH(2);  q_H(aH,2,SL(2), l,acc);
  PH(3);  q_H(aH,3,SL(3), l,acc);
  PACK_GATE();
  // ---- a-proj (f32-grade) ----
  PH(4);  bias_init(bap,cb,acc); q_HL(aH,aLo,0,SL(4), l,acc);
  PH(5);  q_HL(aH,aLo,1,SL(5), l,acc);
  PH(6);  q_HL(aH,aLo,2,SL(6), l,acc);
  PH(7);  q_HL(aH,aLo,3,SL(7), l,acc);
  PH(8);  q_H(aH,0,SL(8), l,acc);
  PH(9);  q_H(aH,1,SL(9), l,acc);
  PH(10); q_H(aH,2,SL(10),l,acc);
  PH(11); q_H(aH,3,SL(11),l,acc);
  // ---- xa = a*sig(ga)*mask -> park bf16 pair-order in own buf region ----
  {
    unsigned char* xr = buf + wv*4096;
    #pragma unroll
    for (int n=0;n<8;n++){
      #pragma unroll
      for (int rp=0;rp<2;rp++){
        float g0 = h2f((unsigned short)(gpk[n*2+rp] & 0xffffu));
        float g1 = h2f((unsigned short)(gpk[n*2+rp] >> 16));
        float a0 = acc[n][2*rp]  *g0*mk[2*rp];
        float a1 = acc[n][2*rp+1]*g1*mk[2*rp+1];
        *(unsigned*)(xr + (n*2+rp)*256 + l*4) = pack2(a0,a1);
      }
    }
  }
  // ---- b-gate (hi-only), pack ----
  PH(12); bias_init(bbg,cb,acc); q_H(aH,0,SL(12),l,acc);
  PH(13); q_H(aH,1,SL(13),l,acc);
  PH(14); q_H(aH,2,SL(14),l,acc);
  PH(15); q_H(aH,3,SL(15),l,acc);
  PACK_GATE();
  // ---- b-proj ----
  PH(16); bias_init(bbp,cb,acc); q_HL(aH,aLo,0,SL(16),l,acc);
  PH(17); q_HL(aH,aLo,1,SL(17),l,acc);
  PH(18); q_HL(aH,aLo,2,SL(18),l,acc);
  PH(19); q_HL(aH,aLo,3,SL(19),l,acc);     // last aLo use
  PH(20); q_H(aH,0,SL(20),l,acc);
  PH(21); q_H(aH,1,SL(21),l,acc);
  PH(22); q_H(aH,2,SL(22),l,acc);
  PH(23); q_H(aH,3,SL(23),l,acc);
  // ---- x = xa*b ; LN(x) in-register ; xn -> buf ; extract a2 (wave-local) ----
  bf16x8 a2[4];
  {
    f32x4 xv[8];
    const unsigned char* xr = buf + wv*4096;
    #pragma unroll
    for (int n=0;n<8;n++){
      #pragma unroll
      for (int rp=0;rp<2;rp++){
        float g0 = h2f((unsigned short)(gpk[n*2+rp] & 0xffffu));
        float g1 = h2f((unsigned short)(gpk[n*2+rp] >> 16));
        unsigned w = *(const unsigned*)(xr + (n*2+rp)*256 + l*4);
        float b0 = acc[n][2*rp]  *g0*mk[2*rp];
        float b1 = acc[n][2*rp+1]*g1*mk[2*rp+1];
        xv[n][2*rp]   = bf2f(w & 0xffffu)*b0;
        xv[n][2*rp+1] = bf2f(w >> 16)   *b1;
      }
    }
    float lw8[8], lb8[8];
    #pragma unroll
    for (int n=0;n<8;n++){ lw8[n]=lnow[n*16+cb]; lb8[n]=lnob[n*16+cb]; }
    #pragma unroll
    for (int r=0;r<4;r++){
      float s=0.f;
      #pragma unroll
      for (int n=0;n<8;n++) s += xv[n][r];
      #pragma unroll
      for (int mm=1; mm<16; mm<<=1) s += __shfl_xor(s,mm);
      float mu = s*(1.0f/128.0f);
      float ss=0.f;
      #pragma unroll
      for (int n=0;n<8;n++){ float d = xv[n][r]-mu; ss += d*d; }
      #pragma unroll
      for (int mm=1; mm<16; mm<<=1) ss += __shfl_xor(ss,mm);
      float rstd = rsqrtf(ss*(1.0f/128.0f) + 1e-5f);
      int row = row0 + g4 + r;
      int swz = (row&7)<<4;
      #pragma unroll
      for (int n=0;n<8;n++){
        int colb = (n*16+cb)*2;
        float vvv = (xv[n][r]-mu)*rstd*lw8[n]+lb8[n];
        *(unsigned short*)(buf + row*256 + (colb ^ swz)) = f2bf(vvv);
      }
    }
    extract4(buf, row0, l, a2);   // own rows; same-wave ds ordering
  }
  // ---- g-gate (zn@Wg, hi-only) -> pack ; final proj (xn@Wz) ----
  PH(24); bias_init(bgg,cb,acc); q_H(aH,0,SL(24),l,acc);
  PH(25); q_H(aH,1,SL(25),l,acc);
  PH(26); q_H(aH,2,SL(26),l,acc);
  PH(27); q_H(aH,3,SL(27),l,acc);
  PACK_GATE();
  PH(28); bias_init(bz,cb,acc); q_H(a2,0,SL(28),l,acc);
  PH(29); q_H(a2,1,SL(29),l,acc);
  PH(30); q_H(a2,2,SL(30),l,acc);
  PH(31); q_H(a2,3,SL(31),l,acc);
  // ---- epilogue: out = o * sig(gv) ----
  #pragma unroll
  for (int n=0;n<8;n++){
    #pragma unroll
    for (int r=0;r<4;r++){
      int row = row0 + g4 + r;
      float gg = h2f((unsigned short)((gpk[n*2+(r>>1)] >> ((r&1)*16)) & 0xffffu));
      out[(size_t)(pos0+row)*CC + n*16 + cb] = acc[n][r]*gg;
    }
  }
#undef PH
#undef SL
#undef PACK_GATE
}

extern "C" void kernel_launch(void* const* d_in, const int* in_sizes, int n_in,
                              void* d_out, int out_size, void* d_ws, size_t ws_size,
                              hipStream_t stream){
  const float* z     = (const float*)d_in[0];
  const float* mask  = (const float*)d_in[1];
  const float* w_ap  = (const float*)d_in[2];
  const float* b_ap  = (const float*)d_in[3];
  const float* w_bp  = (const float*)d_in[4];
  const float* b_bp  = (const float*)d_in[5];
  const float* w_ag  = (const float*)d_in[6];
  const float* b_ag  = (const float*)d_in[7];
  const float* w_bg  = (const float*)d_in[8];
  const float* b_bg  = (const float*)d_in[9];
  const float* w_g   = (const float*)d_in[10];
  const float* b_g   = (const float*)d_in[11];
  const float* w_z   = (const float*)d_in[12];
  const float* b_z   = (const float*)d_in[13];
  const float* ln_in_w  = (const float*)d_in[14];
  const float* ln_in_b  = (const float*)d_in[15];
  const float* ln_out_w = (const float*)d_in[16];
  const float* ln_out_b = (const float*)d_in[17];

  unsigned short* wfrag = (unsigned short*)d_ws;   // 8 planes * 32KB = 256KB

  k0_wprep<<<64, 256, 0, stream>>>(w_ap, w_ag, w_bp, w_bg, w_g, w_z, wfrag);
  k_fused<<<NB, TPB, 0, stream>>>(z, mask, b_ap, b_ag, b_bp, b_bg, b_g, b_z,
                                  ln_in_w, ln_in_b, ln_out_w, ln_out_b,
                                  wfrag, (float*)d_out);
}

// Round 15
// 111.188 us; speedup vs baseline: 1.6778x; 1.6778x over previous
//
#include <hip/hip_runtime.h>
#include <hip/hip_bf16.h>

#define NN 384
#define CC 128
#define PP (NN*NN)      // 147456 positions
#define PB 64           // positions per block
#define NB (PP/PB)      // 2304 blocks
#define TPB 256         // 4 waves; each wave owns one 16-row stripe (16x16x32 MFMA)

typedef __attribute__((ext_vector_type(8))) short bf16x8;
typedef __attribute__((ext_vector_type(4))) float f32x4;
typedef __attribute__((ext_vector_type(8))) unsigned short u16x8;

// 8 weight planes (32KB each) in PHASE order:
// 0 AGH, 1 APH, 2 APL, 3 BGH, 4 BPH, 5 BPL, 6 G, 7 Z
// Plane layout (R7/R12-proven): chunk (k0*8+n)*64+l holds
// W[n*16+(l&15)][k0*32+(l>>4)*8 .. +7], k0 in [0,4).
// Quarter q = bytes [q*8192, q*8192+8192).

__device__ __forceinline__ unsigned short f2bf(float f){
  __hip_bfloat16 h = __float2bfloat16(f);
  return __builtin_bit_cast(unsigned short, h);
}
__device__ __forceinline__ float bf2f(unsigned h){ return __uint_as_float(h<<16); }
__device__ __forceinline__ unsigned pack2(float a, float b){
  return (unsigned)f2bf(a) | ((unsigned)f2bf(b)<<16);
}
__device__ __forceinline__ float sigmoidf_(float x){
  return __fdividef(1.0f, 1.0f + __expf(-x));
}

// ---------------------------------------------------------------------------
__global__ __launch_bounds__(256) void k0_wprep(
    const float* __restrict__ wap, const float* __restrict__ wag,
    const float* __restrict__ wbp, const float* __restrict__ wbg,
    const float* __restrict__ wg,  const float* __restrict__ wz,
    unsigned short* __restrict__ wfrag){
  int tid = blockIdx.x*256 + threadIdx.x;      // 0..16383
  int plane = tid >> 11, chunk = tid & 2047;
  const float* W = (plane==0) ? wag
                 : (plane==1||plane==2) ? wap
                 : (plane==3) ? wbg
                 : (plane==4||plane==5) ? wbp
                 : (plane==6) ? wg : wz;
  bool lo = (plane==2)||(plane==5);
  int k0 = chunk >> 9, n = (chunk >> 6) & 7, l = chunk & 63;
  int o  = n*16 + (l & 15);
  int kb = k0*32 + ((l>>4)<<3);
  const float* s = W + o*128 + kb;
  u16x8 v;
  #pragma unroll
  for (int e=0;e<8;e++){
    float w = s[e];
    unsigned short hh = f2bf(w);
    v[e] = lo ? f2bf(w - bf2f(hh)) : hh;
  }
  *(u16x8*)(wfrag + (size_t)tid*8) = v;
}

// ---------------------------------------------------------------------------
// Stage one 8KB plane-quarter into a slot (global_load_lds, zero staging regs).
// ---------------------------------------------------------------------------
__device__ __forceinline__ void stage_q(const unsigned char* __restrict__ src_base,
                                        unsigned char* slot, int t){
  int wv = t>>6, l = t&63;
  const unsigned char* src = src_base + wv*2048 + l*16;
  unsigned char* dst = slot + wv*2048;
  #pragma unroll
  for (int i=0;i<2;i++)
    __builtin_amdgcn_global_load_lds(
        (const __attribute__((address_space(1))) unsigned int*)(src + i*1024),
        (__attribute__((address_space(3))) unsigned int*)(dst + i*1024),
        16, 0, 0);
}

// ---------------------------------------------------------------------------
// Quarter passes (k0=q fixed): 8 n-frags. Slot offset n*1024 + l*16.
// A-frag: row=row0+(l&15), k=q*32+(l>>4)*8+e. D: row=row0+(l>>4)*4+r, col=n*16+(l&15).
// ---------------------------------------------------------------------------
__device__ __forceinline__ void q_H(const bf16x8* a, int q,
    const unsigned char* slot, int l, f32x4* acc){
  #pragma unroll
  for (int n=0;n<8;n++){
    bf16x8 f = *(const bf16x8*)(slot + n*1024 + l*16);
    acc[n] = __builtin_amdgcn_mfma_f32_16x16x32_bf16(a[q], f, acc[n], 0,0,0);
  }
}
__device__ __forceinline__ void q_HL(const bf16x8* aH, const bf16x8* aL, int q,
    const unsigned char* slot, int l, f32x4* acc){
  #pragma unroll
  for (int n=0;n<8;n++){
    bf16x8 f = *(const bf16x8*)(slot + n*1024 + l*16);
    acc[n] = __builtin_amdgcn_mfma_f32_16x16x32_bf16(aH[q], f, acc[n], 0,0,0);
    acc[n] = __builtin_amdgcn_mfma_f32_16x16x32_bf16(aL[q], f, acc[n], 0,0,0);
  }
}
__device__ __forceinline__ void bias_init(const float* __restrict__ b, int cb,
                                          f32x4* acc){
  #pragma unroll
  for (int n=0;n<8;n++){
    float v = b[n*16 + cb];
    f32x4 iv = {v,v,v,v};
    acc[n]=iv;
  }
}
// A-frag extraction from [row][col] XOR-swizzled bf16 tile (R7/R12-proven).
__device__ __forceinline__ void extract4(const unsigned char* base, int row0,
                                         int l, bf16x8 a[4]){
  int row = row0 + (l&15);
  int swz = (row&7)<<4;
  #pragma unroll
  for (int k0=0;k0<4;k0++){
    unsigned off = (unsigned)(row*256 + ((((l>>4)<<4) + (k0<<6)) ^ swz));
    a[k0] = *(const bf16x8*)(base + off);
  }
}

// ---------------------------------------------------------------------------
// Fused kernel: 32 quarter-phases, 2-slot rotation, stage-1-ahead (R13 skeleton).
// LDS 32KB: buf[0,16K) zn(H then L)->xn, ALL wave-local ; slots [16K,32K).
// ALL-f32 register dataflow: gates sigmoid'ed in place, xa kept in regs.
// Peak live ~ gA32+gB32+prj32+aH16+aLo16+temps ~160 < 256 (2 waves/SIMD).
// ---------------------------------------------------------------------------
__global__ __launch_bounds__(TPB,2) void k_fused(
    const float* __restrict__ z, const float* __restrict__ mask,
    const float* __restrict__ bap, const float* __restrict__ bag,
    const float* __restrict__ bbp, const float* __restrict__ bbg,
    const float* __restrict__ bgg, const float* __restrict__ bz,
    const float* __restrict__ lniw, const float* __restrict__ lnib,
    const float* __restrict__ lnow, const float* __restrict__ lnob,
    const unsigned short* __restrict__ wfrag,
    float* __restrict__ out){
  __shared__ unsigned char lds[32768];
  unsigned char* buf = lds;             // 16KB: zn -> xn (wave-local 4K regions)
  const unsigned char* wfrag8 = (const unsigned char*)wfrag;
  const int t = threadIdx.x;
  const int pos0 = blockIdx.x * PB;
  const int wv = t>>6, l = t&63;
  const int h2 = (t>>5)&1;              // 32-lane group within wave
  const int c4 = (t&31)<<2;
  const int row0 = wv*16;

  // prologue: stage quarter 0 (AGH q0) -> slot 0
  stage_q(wfrag8, lds + 16384, t);

  // ---- P1: LN(z) WAVE-LOCAL (2 rows/iter), znH -> buf, znL packed in regs ----
  unsigned plr[16];
  {
    float4 lw = *(const float4*)(lniw + c4);
    float4 lb = *(const float4*)(lnib + c4);
    #pragma unroll
    for (int it=0; it<8; ++it){
      int row = row0 + it*2 + h2;
      float4 v = *(const float4*)(z + (size_t)(pos0+row)*CC + c4);
      float s = v.x+v.y+v.z+v.w;
      #pragma unroll
      for (int mm=1; mm<32; mm<<=1) s += __shfl_xor(s,mm);
      float mu = s*(1.0f/128.0f);
      float d0=v.x-mu, d1=v.y-mu, d2=v.z-mu, d3=v.w-mu;
      float ss = d0*d0+d1*d1+d2*d2+d3*d3;
      #pragma unroll
      for (int mm=1; mm<32; mm<<=1) ss += __shfl_xor(ss,mm);
      float rstd = rsqrtf(ss*(1.0f/128.0f) + 1e-5f);
      float n0=d0*rstd*lw.x+lb.x, n1=d1*rstd*lw.y+lb.y;
      float n2=d2*rstd*lw.z+lb.z, n3=d3*rstd*lw.w+lb.w;
      unsigned short hh0=f2bf(n0), hh1=f2bf(n1), hh2=f2bf(n2), hh3=f2bf(n3);
      unsigned off = (unsigned)(row*256 + ((c4<<1) ^ ((row&7)<<4)));
      *(uint2*)(buf + off) = make_uint2((unsigned)hh0|((unsigned)hh1<<16),
                                        (unsigned)hh2|((unsigned)hh3<<16));
      plr[it*2]   = pack2(n0-bf2f(hh0), n1-bf2f(hh1));
      plr[it*2+1] = pack2(n2-bf2f(hh2), n3-bf2f(hh3));
    }
  }
  // aH from znH (same-wave ds ordering; R8-proven pattern)
  bf16x8 aH[4], aLo[4];
  extract4(buf, row0, l, aH);
  // overwrite with znL residuals (wave-local), then aLo
  #pragma unroll
  for (int it=0; it<8; ++it){
    int row = row0 + it*2 + h2;
    unsigned off = (unsigned)(row*256 + ((c4<<1) ^ ((row&7)<<4)));
    *(uint2*)(buf + off) = make_uint2(plr[it*2], plr[it*2+1]);
  }
  extract4(buf, row0, l, aLo);

  const int cb = l&15;            // D col-within-16 / A row-within-16
  const int g4 = (l>>4)<<2;       // D row-quad base

  float mk[4];
  #pragma unroll
  for (int r=0;r<4;r++) mk[r] = mask[pos0 + row0 + g4 + r];

  f32x4 gA[8], gB[8], prj[8];     // all-f32 dataflow

#define SL(p) (lds + 16384 + (((p)&1)<<13))
#define PH(p) do{ __syncthreads(); \
    if ((p)+1 < 32) stage_q(wfrag8 + ((size_t)((p)+1))*8192, SL((p)+1), t); }while(0)
#define SIG_INPLACE(A) do{ \
    _Pragma("unroll") \
    for (int n=0;n<8;n++) \
      _Pragma("unroll") \
      for (int r=0;r<4;r++) (A)[n][r] = sigmoidf_((A)[n][r]); \
  }while(0)

  // ---- a-gate (hi-only) -> gA, sigmoid in place ----
  PH(0);  bias_init(bag,cb,gA); q_H(aH,0,SL(0), l,gA);
  PH(1);  q_H(aH,1,SL(1), l,gA);
  PH(2);  q_H(aH,2,SL(2), l,gA);
  PH(3);  q_H(aH,3,SL(3), l,gA);
  SIG_INPLACE(gA);
  // ---- a-proj (f32-grade) -> prj ----
  PH(4);  bias_init(bap,cb,prj); q_HL(aH,aLo,0,SL(4), l,prj);
  PH(5);  q_HL(aH,aLo,1,SL(5), l,prj);
  PH(6);  q_HL(aH,aLo,2,SL(6), l,prj);
  PH(7);  q_HL(aH,aLo,3,SL(7), l,prj);
  PH(8);  q_H(aH,0,SL(8), l,prj);
  PH(9);  q_H(aH,1,SL(9), l,prj);
  PH(10); q_H(aH,2,SL(10),l,prj);
  PH(11); q_H(aH,3,SL(11),l,prj);
  // ---- xa = prj*sig(ga)*mask -> keep in gA (registers; no LDS park) ----
  #pragma unroll
  for (int n=0;n<8;n++)
    #pragma unroll
    for (int r=0;r<4;r++)
      gA[n][r] = prj[n][r]*gA[n][r]*mk[r];
  // ---- b-gate (hi-only) -> gB, sigmoid in place ----
  PH(12); bias_init(bbg,cb,gB); q_H(aH,0,SL(12),l,gB);
  PH(13); q_H(aH,1,SL(13),l,gB);
  PH(14); q_H(aH,2,SL(14),l,gB);
  PH(15); q_H(aH,3,SL(15),l,gB);
  SIG_INPLACE(gB);
  // ---- b-proj -> prj ----
  PH(16); bias_init(bbp,cb,prj); q_HL(aH,aLo,0,SL(16),l,prj);
  PH(17); q_HL(aH,aLo,1,SL(17),l,prj);
  PH(18); q_HL(aH,aLo,2,SL(18),l,prj);
  PH(19); q_HL(aH,aLo,3,SL(19),l,prj);     // last aLo use
  PH(20); q_H(aH,0,SL(20),l,prj);
  PH(21); q_H(aH,1,SL(21),l,prj);
  PH(22); q_H(aH,2,SL(22),l,prj);
  PH(23); q_H(aH,3,SL(23),l,prj);
  // ---- x = xa * (prj*sig(gb)*mask) in gA ; LN(x) ; xn -> buf ; extract a2 ----
  bf16x8 a2[4];
  {
    #pragma unroll
    for (int n=0;n<8;n++)
      #pragma unroll
      for (int r=0;r<4;r++)
        gA[n][r] *= prj[n][r]*gB[n][r]*mk[r];
    float lw8[8], lb8[8];
    #pragma unroll
    for (int n=0;n<8;n++){ lw8[n]=lnow[n*16+cb]; lb8[n]=lnob[n*16+cb]; }
    #pragma unroll
    for (int r=0;r<4;r++){
      float s=0.f;
      #pragma unroll
      for (int n=0;n<8;n++) s += gA[n][r];
      #pragma unroll
      for (int mm=1; mm<16; mm<<=1) s += __shfl_xor(s,mm);
      float mu = s*(1.0f/128.0f);
      float ss=0.f;
      #pragma unroll
      for (int n=0;n<8;n++){ float d = gA[n][r]-mu; ss += d*d; }
      #pragma unroll
      for (int mm=1; mm<16; mm<<=1) ss += __shfl_xor(ss,mm);
      float rstd = rsqrtf(ss*(1.0f/128.0f) + 1e-5f);
      int row = row0 + g4 + r;
      int swz = (row&7)<<4;
      #pragma unroll
      for (int n=0;n<8;n++){
        int colb = (n*16+cb)*2;
        float vvv = (gA[n][r]-mu)*rstd*lw8[n]+lb8[n];
        *(unsigned short*)(buf + row*256 + (colb ^ swz)) = f2bf(vvv);
      }
    }
    extract4(buf, row0, l, a2);   // own rows; same-wave ds ordering
  }
  // ---- g-gate (zn@Wg, hi-only) -> gB, sigmoid ; final proj (xn@Wz) -> prj ----
  PH(24); bias_init(bgg,cb,gB); q_H(aH,0,SL(24),l,gB);
  PH(25); q_H(aH,1,SL(25),l,gB);
  PH(26); q_H(aH,2,SL(26),l,gB);
  PH(27); q_H(aH,3,SL(27),l,gB);
  SIG_INPLACE(gB);
  PH(28); bias_init(bz,cb,prj); q_H(a2,0,SL(28),l,prj);
  PH(29); q_H(a2,1,SL(29),l,prj);
  PH(30); q_H(a2,2,SL(30),l,prj);
  PH(31); q_H(a2,3,SL(31),l,prj);
  // ---- epilogue: out = prj * gB ----
  #pragma unroll
  for (int n=0;n<8;n++){
    #pragma unroll
    for (int r=0;r<4;r++){
      int row = row0 + g4 + r;
      out[(size_t)(pos0+row)*CC + n*16 + cb] = prj[n][r]*gB[n][r];
    }
  }
#undef PH
#undef SL
#undef SIG_INPLACE
}

extern "C" void kernel_launch(void* const* d_in, const int* in_sizes, int n_in,
                              void* d_out, int out_size, void* d_ws, size_t ws_size,
                              hipStream_t stream){
  const float* z     = (const float*)d_in[0];
  const float* mask  = (const float*)d_in[1];
  const float* w_ap  = (const float*)d_in[2];
  const float* b_ap  = (const float*)d_in[3];
  const float* w_bp  = (const float*)d_in[4];
  const float* b_bp  = (const float*)d_in[5];
  const float* w_ag  = (const float*)d_in[6];
  const float* b_ag  = (const float*)d_in[7];
  const float* w_bg  = (const float*)d_in[8];
  const float* b_bg  = (const float*)d_in[9];
  const float* w_g   = (const float*)d_in[10];
  const float* b_g   = (const float*)d_in[11];
  const float* w_z   = (const float*)d_in[12];
  const float* b_z   = (const float*)d_in[13];
  const float* ln_in_w  = (const float*)d_in[14];
  const float* ln_in_b  = (const float*)d_in[15];
  const float* ln_out_w = (const float*)d_in[16];
  const float* ln_out_b = (const float*)d_in[17];

  unsigned short* wfrag = (unsigned short*)d_ws;   // 8 planes * 32KB = 256KB

  k0_wprep<<<64, 256, 0, stream>>>(w_ap, w_ag, w_bp, w_bg, w_g, w_z, wfrag);
  k_fused<<<NB, TPB, 0, stream>>>(z, mask, b_ap, b_ag, b_bp, b_bg, b_g, b_z,
                                  ln_in_w, ln_in_b, ln_out_w, ln_out_b,
                                  wfrag, (float*)d_out);
}